// Round 9
// baseline (9010.509 us; speedup 1.0000x reference)
//
#include <hip/hip_runtime.h>
#include <hip/hip_bf16.h>

// Problem constants
#define B_    32
#define TO_   256
#define T_    257        // To+1 decode steps
#define H_    512
#define V_    10000
#define TI_   1024
#define NROW_ 8224       // T_*B_
#define NB_   256        // blocks in cooperative kernel
#define SPINCAP 150000

using f32x4 = __attribute__((ext_vector_type(4))) float;
using s16x8 = __attribute__((ext_vector_type(8))) short;
typedef unsigned long long ull;

struct Ptrs {
  const int* padded;
  const float* enc;
  const float* emb;
  const float *Wih0, *Whh0, *bih0, *bhh0;
  const float *Wih1, *Whh1, *bih1, *bhh1;
  const float *W1, *b1, *W2, *b2;
  float* out;
  // workspace
  unsigned short *mlpin;   // [257][32][1024] bf16  (=[h1 | att_c])
  unsigned short *embt;    // [257][32][512] bf16; tanhv overlays after kA
  unsigned short *tanhv;   // [8224][512] bf16 (== embt region)
  unsigned short *W0c;     // [2048][1536] bf16 rows g'=j*4+q = [Wih0 | Whh0]; W2b overlays
  unsigned short *W1c;     // [2048][1024] bf16 rows g'=j*4+q = [Wih1 | Whh1]
  unsigned short *W1b;     // [512][1024] bf16
  unsigned short *W2b;     // [10000][512] bf16 (== W0c region, kprep2)
  float *bias0c, *bias1c;  // [2048] combined biases, gate-interleaved
  float *u;                // [2][32][512] f32 unnormalized context (sc1 atomicAdd)
  float *Zb;               // [2][32] softmax denominators (sc1 atomicAdd)
  unsigned short *Xh0;     // [2][32][512] bf16 h0 state
  unsigned short *Xh1;     // [2][32][512] bf16 h1 state
  float *Xh1f;             // [2][32][512] f32 h1 state (attention staging)
  unsigned *arrX;          // [128*4] S1-done flags (GEMM blocks)
  unsigned *arrY;          // [256*4] pre-S34-ready flags (all blocks)
  unsigned *marr;          // [256*4] S34-done flags
  unsigned *dX, *dY, *dM;  // dummy flag arrays for the sync-skeleton measurement
  unsigned *ibar;          // [256*4] init barrier flags
  float *rowsum;           // [8224]
  float *lablog;           // [8224]
};

__device__ __forceinline__ unsigned short f2b(float f){
  __hip_bfloat16 h = __float2bfloat16(f);
  unsigned short r; __builtin_memcpy(&r, &h, 2); return r;
}
__device__ __forceinline__ float b2f(unsigned short u){
  unsigned v = ((unsigned)u) << 16; float f; __builtin_memcpy(&f, &v, 4); return f;
}
__device__ __forceinline__ float sigf(float x){ return 1.f / (1.f + expf(-x)); }

// ---- agent-scope (sc1, L3) relaxed atomics ----
__device__ __forceinline__ float aldf(const float* p){
  return __hip_atomic_load(p, __ATOMIC_RELAXED, __HIP_MEMORY_SCOPE_AGENT);
}
__device__ __forceinline__ unsigned aldw(const unsigned* p){
  return __hip_atomic_load(p, __ATOMIC_RELAXED, __HIP_MEMORY_SCOPE_AGENT);
}
__device__ __forceinline__ ull aldu(const ull* p){
  return __hip_atomic_load(p, __ATOMIC_RELAXED, __HIP_MEMORY_SCOPE_AGENT);
}
__device__ __forceinline__ void astf(float* p, float v){
  __hip_atomic_store(p, v, __ATOMIC_RELAXED, __HIP_MEMORY_SCOPE_AGENT);
}
__device__ __forceinline__ void astu(ull* p, ull v){
  __hip_atomic_store(p, v, __ATOMIC_RELAXED, __HIP_MEMORY_SCOPE_AGENT);
}
__device__ __forceinline__ void astw(unsigned* p, unsigned v){
  __hip_atomic_store(p, v, __ATOMIC_RELAXED, __HIP_MEMORY_SCOPE_AGENT);
}
#define DRAIN asm volatile("s_waitcnt vmcnt(0)" ::: "memory")

// init-time full-grid flag barrier (bounded)
__device__ __forceinline__ void gbarInit(unsigned* bar){
  DRAIN; __syncthreads();
  if (threadIdx.x < 64){
    const int l = threadIdx.x;
    if (l == 0) astw(bar + blockIdx.x * 4, 1u);
    int spin = 0;
    for (;;){
      unsigned f0 = aldw(bar + (l      ) * 4);
      unsigned f1 = aldw(bar + (l +  64) * 4);
      unsigned f2 = aldw(bar + (l + 128) * 4);
      unsigned f3 = aldw(bar + (l + 192) * 4);
      if (__all((f0 >= 1u) & (f1 >= 1u) & (f2 >= 1u) & (f3 >= 1u))) break;
      if (++spin > SPINCAP) break;
      __builtin_amdgcn_s_sleep(1);
    }
  }
  __syncthreads();
}

// ------------------------------------------------------------------
__global__ __launch_bounds__(256) void kprep(Ptrs P){
  const int stride = gridDim.x * blockDim.x;
  const int i0 = blockIdx.x * blockDim.x + threadIdx.x;
  for (int i = i0; i < 128 * 4; i += stride){ P.arrX[i] = 0u; P.dX[i] = 0u; }
  for (int i = i0; i < 256 * 4; i += stride){
    P.arrY[i] = 0u; P.marr[i] = 0u; P.ibar[i] = 0u; P.dY[i] = 0u; P.dM[i] = 0u;
  }
  for (int i = i0; i < T_ * B_ * 512; i += stride){
    int k = i & 511, tb = i >> 9, b = tb & 31, t = tb >> 5;
    int tok = (t == 0) ? 1 : P.padded[b * TO_ + (t - 1)];
    P.embt[i] = f2b(P.emb[(size_t)tok * 512 + k]);
  }
  for (int i = i0; i < 2048 * 1536; i += stride){
    int k = i % 1536, gp = i / 1536;
    int j = gp >> 2, q = gp & 3, g = q * 512 + j;
    float v = (k < 1024) ? P.Wih0[(size_t)g * 1024 + k] : P.Whh0[(size_t)g * 512 + (k - 1024)];
    P.W0c[i] = f2b(v);
  }
  for (int i = i0; i < 2048 * 1024; i += stride){
    int k = i & 1023, gp = i >> 10;
    int j = gp >> 2, q = gp & 3, g = q * 512 + j;
    float v = (k < 512) ? P.Wih1[(size_t)g * 512 + k] : P.Whh1[(size_t)g * 512 + (k - 512)];
    P.W1c[i] = f2b(v);
  }
  for (int i = i0; i < 2048; i += stride){
    int j = i >> 2, q = i & 3, g = q * 512 + j;
    P.bias0c[i] = P.bih0[g] + P.bhh0[g];
    P.bias1c[i] = P.bih1[g] + P.bhh1[g];
  }
  for (int i = i0; i < 512 * 1024; i += stride) P.W1b[i] = f2b(P.W1[i]);
  for (int i = i0; i < NROW_; i += stride) P.rowsum[i] = 0.f;
}

__global__ __launch_bounds__(256) void kprep2(Ptrs P){
  const int stride = gridDim.x * blockDim.x;
  const int i0 = blockIdx.x * blockDim.x + threadIdx.x;
  for (int i = i0; i < V_ * 512; i += stride) P.W2b[i] = f2b(P.W2[i]);
}

// ------------------------------------------------------------------
// Phase A (R8 structure + a 257-iteration sync-only skeleton pre-loop on
// dummy flags dX/dY/dM: measures pure rendezvous cost by subtraction vs R8).
__global__ __launch_bounds__(256, 1) void kA(Ptrs P){
  __shared__ __align__(16) unsigned short enc_s[128 * 512]; // 128 KB, XOR-swizzled
  __shared__ float h1_s[512];
  __shared__ float w_s[128];
  __shared__ float gate_s[2][32][17];
  __shared__ float h_s[32][4];
  __shared__ float zred[2];
  const int bb = blockIdx.x, tid = threadIdx.x;
  const int b_att = bb >> 3, tc = bb & 7;

  { // stage encoder slice -> LDS bf16, byte^((row&7)<<4) swizzle
    const float* ep = P.enc + ((size_t)b_att * TI_ + (size_t)tc * 128) * H_;
    for (int idx = tid; idx < 128 * 512; idx += 256){
      int row = idx >> 9;
      unsigned byteoff = ((unsigned)idx * 2u) ^ ((unsigned)(row & 7) << 4);
      enc_s[byteoff >> 1] = f2b(ep[idx]);
    }
  }
  { // init recurrent state
    int g = bb * 256 + tid;
    if (g < 32768){ astf(P.u + g, 0.f); astf(P.Xh1f + g, 0.f); }
    if (g < 16384){ astw((unsigned*)P.Xh0 + g, 0u); astw((unsigned*)P.Xh1 + g, 0u); }
    if (g < 64) astf(P.Zb + g, (g >= 32) ? 1.f : 0.f);   // Zb[1]=1 for t=0
  }
  gbarInit(P.ibar);

  const bool isGemm = bb < 128;

  // ================= MEASUREMENT: sync-only skeleton, 257 iters =================
  // Faithful copy of the real loop's rendezvous pattern, zero data work.
  for (int k = 1; k <= T_; ++k){
    const unsigned kv = (unsigned)k;
    if (isGemm){
      if (k > 1){
        if (tid < 64){
          const unsigned want = kv - 1u;
          int spin = 0;
          for (;;){
            unsigned f0 = aldw(P.dM + (tid      ) * 4);
            unsigned f1 = aldw(P.dM + (tid +  64) * 4);
            unsigned f2 = aldw(P.dM + (tid + 128) * 4);
            unsigned f3 = aldw(P.dM + (tid + 192) * 4);
            if (__all((f0 >= want) & (f1 >= want) & (f2 >= want) & (f3 >= want))) break;
            if (++spin > SPINCAP) break;
            __builtin_amdgcn_s_sleep(1);
          }
        }
        __syncthreads();
      }
      DRAIN; __syncthreads();
      if (tid == 0) astw(P.dX + bb * 4, kv);
      if (tid < 64){
        int spin = 0;
        for (;;){
          unsigned f0 = aldw(P.dX + tid * 4), f1 = aldw(P.dX + (tid + 64) * 4);
          if (__all((f0 >= kv) & (f1 >= kv))) break;
          if (++spin > SPINCAP) break;
          __builtin_amdgcn_s_sleep(1);
        }
      }
      __syncthreads();
      DRAIN; __syncthreads();
      if (tid == 0) astw(P.dY + bb * 4, kv);
    } else if (bb < 160){
      if (k > 1){
        const int b = bb - 128;
        if (tid < 64){
          const unsigned want = kv - 1u;
          int spin = 0;
          for (;;){
            unsigned f = (tid < 8) ? aldw(P.dM + (b * 8 + tid) * 4) : want;
            if (__all(f >= want)) break;
            if (++spin > SPINCAP) break;
            __builtin_amdgcn_s_sleep(1);
          }
        }
      }
      __syncthreads();
      if (tid == 0) astw(P.dY + bb * 4, kv);
    } else {
      DRAIN; __syncthreads();
      if (tid == 0) astw(P.dY + bb * 4, kv);
    }
    if (tid < 64){
      int spin = 0;
      for (;;){
        unsigned f0 = aldw(P.dY + (tid      ) * 4);
        unsigned f1 = aldw(P.dY + (tid +  64) * 4);
        unsigned f2 = aldw(P.dY + (tid + 128) * 4);
        unsigned f3 = aldw(P.dY + (tid + 192) * 4);
        if (__all((f0 >= kv) & (f1 >= kv) & (f2 >= kv) & (f3 >= kv))) break;
        if (++spin > SPINCAP) break;
        __builtin_amdgcn_s_sleep(1);
      }
    }
    __syncthreads();
    DRAIN; __syncthreads();
    if (tid == 0) astw(P.dM + (b_att * 8 + tc) * 4, kv);
  }
  // ================= end measurement skeleton =================

  const int wv = tid >> 6, l = tid & 63, lr = l & 15, lk = l >> 4;
  const int bh = wv & 1, kh = wv >> 1;          // batch-half, K-half
  const int batch = bh * 16 + lr;
  const int eidx = tid - 128, eb = eidx >> 2, ejl = eidx & 3;
  float c0r = 0.f, c1r = 0.f;

  for (int t = 0; t < T_; ++t){
    const int p = t & 1, pp = p ^ 1;
    const unsigned tv = (unsigned)t + 1u;
    if (isGemm){
      // ---- S1a: e-seg + h0-seg MFMAs (independent of attc(t-1)) ----
      const unsigned short* Brow = P.W0c + (size_t)(bb * 16 + lr) * 1536;
      const unsigned short* Erow = P.embt + ((size_t)t * 32 + batch) * 512;
      f32x4 acc = {0.f, 0.f, 0.f, 0.f};
      #pragma unroll
      for (int ks = 0; ks < 8; ++ks){
        const int kb = (kh * 8 + ks) * 32 + lk * 8;
        s16x8 a = *(const s16x8*)(Erow + kb);
        s16x8 b = *(const s16x8*)(Brow + kb);
        acc = __builtin_amdgcn_mfma_f32_16x16x32_bf16(a, b, acc, 0, 0, 0);
      }
      {
        const ull* Hrow = (const ull*)(P.Xh0 + pp * 16384 + batch * 512);
        #pragma unroll
        for (int ks = 0; ks < 8; ++ks){
          const int kb = (kh * 8 + ks) * 32 + lk * 8;
          ull d0 = aldu(Hrow + (kb >> 2)), d1 = aldu(Hrow + (kb >> 2) + 1);
          s16x8 a; __builtin_memcpy(&a, &d0, 8); __builtin_memcpy(((char*)&a) + 8, &d1, 8);
          s16x8 b = *(const s16x8*)(Brow + 1024 + kb);
          acc = __builtin_amdgcn_mfma_f32_16x16x32_bf16(a, b, acc, 0, 0, 0);
        }
      }
      // ---- wait: S34(t-1) contributions all in ----
      if (t > 0){
        if (tid < 64){
          const unsigned want = (unsigned)t;
          int spin = 0;
          for (;;){
            unsigned f0 = aldw(P.marr + (tid      ) * 4);
            unsigned f1 = aldw(P.marr + (tid +  64) * 4);
            unsigned f2 = aldw(P.marr + (tid + 128) * 4);
            unsigned f3 = aldw(P.marr + (tid + 192) * 4);
            if (__all((f0 >= want) & (f1 >= want) & (f2 >= want) & (f3 >= want))) break;
            if (++spin > SPINCAP) break;
            __builtin_amdgcn_s_sleep(1);
          }
        }
        __syncthreads();
      }
      // ---- S1b: att_c segment from u[pp]*rZ ----
      {
        const float* Urow = P.u + pp * 16384 + batch * 512;
        const float rZ = 1.f / aldf(P.Zb + pp * 32 + batch);
        #pragma unroll
        for (int ks = 0; ks < 8; ++ks){
          const int kb = (kh * 8 + ks) * 32 + lk * 8;
          ull dd[4];
          dd[0] = aldu((const ull*)(Urow + kb));
          dd[1] = aldu((const ull*)(Urow + kb + 2));
          dd[2] = aldu((const ull*)(Urow + kb + 4));
          dd[3] = aldu((const ull*)(Urow + kb + 6));
          float uf[8]; __builtin_memcpy(uf, dd, 32);
          s16x8 a;
          #pragma unroll
          for (int e = 0; e < 8; ++e) a[e] = (short)f2b(uf[e] * rZ);
          s16x8 b = *(const s16x8*)(Brow + 512 + kb);
          acc = __builtin_amdgcn_mfma_f32_16x16x32_bf16(a, b, acc, 0, 0, 0);
        }
      }
      #pragma unroll
      for (int j = 0; j < 4; ++j) gate_s[kh][bh * 16 + lk * 4 + j][lr] = acc[j];
      __syncthreads();
      if (tid >= 128){
        const float* bs = P.bias0c + bb * 16 + ejl * 4;
        float ii = sigf (gate_s[0][eb][ejl * 4 + 0] + gate_s[1][eb][ejl * 4 + 0] + bs[0]);
        float ff = sigf (gate_s[0][eb][ejl * 4 + 1] + gate_s[1][eb][ejl * 4 + 1] + bs[1]);
        float gg = tanhf(gate_s[0][eb][ejl * 4 + 2] + gate_s[1][eb][ejl * 4 + 2] + bs[2]);
        float oo = sigf (gate_s[0][eb][ejl * 4 + 3] + gate_s[1][eb][ejl * 4 + 3] + bs[3]);
        float cn = ff * c0r + ii * gg; c0r = cn;
        h_s[eb][ejl] = oo * tanhf(cn);
      }
      __syncthreads();
      if (tid < 32){
        unsigned short hb[4];
        #pragma unroll
        for (int jl = 0; jl < 4; ++jl) hb[jl] = f2b(h_s[tid][jl]);
        ull v; __builtin_memcpy(&v, hb, 8);
        astu((ull*)(P.Xh0 + p * 16384 + tid * 512 + bb * 4), v);
      }
      DRAIN; __syncthreads();
      if (tid == 0) astw(P.arrX + bb * 4, tv);
      // ---- arrX wait (128 blocks) ----
      if (tid < 64){
        int spin = 0;
        for (;;){
          unsigned f0 = aldw(P.arrX + tid * 4), f1 = aldw(P.arrX + (tid + 64) * 4);
          if (__all((f0 >= tv) & (f1 >= tv))) break;
          if (++spin > SPINCAP) break;
          __builtin_amdgcn_s_sleep(1);
        }
      }
      __syncthreads();
      // ---- S2: layer-1 gates ----
      {
        const unsigned short* Brow1 = P.W1c + (size_t)(bb * 16 + lr) * 1024;
        const ull* H0r = (const ull*)(P.Xh0 + p * 16384 + batch * 512);
        const ull* H1r = (const ull*)(P.Xh1 + pp * 16384 + batch * 512);
        f32x4 acc2 = {0.f, 0.f, 0.f, 0.f};
        #pragma unroll
        for (int ks = 0; ks < 8; ++ks){
          const int kb = (kh * 8 + ks) * 32 + lk * 8;
          ull d0 = aldu(H0r + (kb >> 2)), d1 = aldu(H0r + (kb >> 2) + 1);
          s16x8 a; __builtin_memcpy(&a, &d0, 8); __builtin_memcpy(((char*)&a) + 8, &d1, 8);
          s16x8 b = *(const s16x8*)(Brow1 + kb);
          acc2 = __builtin_amdgcn_mfma_f32_16x16x32_bf16(a, b, acc2, 0, 0, 0);
        }
        #pragma unroll
        for (int ks = 0; ks < 8; ++ks){
          const int kb = (kh * 8 + ks) * 32 + lk * 8;
          ull d0 = aldu(H1r + (kb >> 2)), d1 = aldu(H1r + (kb >> 2) + 1);
          s16x8 a; __builtin_memcpy(&a, &d0, 8); __builtin_memcpy(((char*)&a) + 8, &d1, 8);
          s16x8 b = *(const s16x8*)(Brow1 + 512 + kb);
          acc2 = __builtin_amdgcn_mfma_f32_16x16x32_bf16(a, b, acc2, 0, 0, 0);
        }
        #pragma unroll
        for (int j = 0; j < 4; ++j) gate_s[kh][bh * 16 + lk * 4 + j][lr] = acc2[j];
      }
      __syncthreads();
      if (tid >= 128){
        const float* bs = P.bias1c + bb * 16 + ejl * 4;
        float ii = sigf (gate_s[0][eb][ejl * 4 + 0] + gate_s[1][eb][ejl * 4 + 0] + bs[0]);
        float ff = sigf (gate_s[0][eb][ejl * 4 + 1] + gate_s[1][eb][ejl * 4 + 1] + bs[1]);
        float gg = tanhf(gate_s[0][eb][ejl * 4 + 2] + gate_s[1][eb][ejl * 4 + 2] + bs[2]);
        float oo = sigf (gate_s[0][eb][ejl * 4 + 3] + gate_s[1][eb][ejl * 4 + 3] + bs[3]);
        float cn = ff * c1r + ii * gg; c1r = cn;
        h_s[eb][ejl] = oo * tanhf(cn);
      }
      __syncthreads();
      if (tid < 32){
        unsigned short hb[4];
        #pragma unroll
        for (int jl = 0; jl < 4; ++jl) hb[jl] = f2b(h_s[tid][jl]);
        ull vb; __builtin_memcpy(&vb, hb, 8);
        astu((ull*)(P.Xh1 + p * 16384 + tid * 512 + bb * 4), vb);
        ull w0, w1;
        __builtin_memcpy(&w0, &h_s[tid][0], 8);
        __builtin_memcpy(&w1, &h_s[tid][2], 8);
        ull* dst = (ull*)P.Xh1f + ((p * 16384 + tid * 512 + bb * 4) >> 1);
        astu(dst, w0); astu(dst + 1, w1);
      }
      DRAIN; __syncthreads();
      if (tid == 0) astw(P.arrY + bb * 4, tv);
      if (tid < 32){                             // mlpin h1: after flag (off-path)
        unsigned short hb[4];
        #pragma unroll
        for (int jl = 0; jl < 4; ++jl) hb[jl] = f2b(h_s[tid][jl]);
        ull vb; __builtin_memcpy(&vb, hb, 8);
        *(ull*)(P.mlpin + ((size_t)t * 32 + tid) * 1024 + bb * 4) = vb;
      }
    } else if (bb < 160){
      if (t > 0){
        const int b = bb - 128;
        if (tid < 64){
          const unsigned want = (unsigned)t;
          int spin = 0;
          for (;;){
            unsigned f = (tid < 8) ? aldw(P.marr + (b * 8 + tid) * 4) : want;
            if (__all(f >= want)) break;
            if (++spin > SPINCAP) break;
            __builtin_amdgcn_s_sleep(1);
          }
        }
        __syncthreads();
        const float rZ = 1.f / aldf(P.Zb + pp * 32 + b);
        ull v = aldu((const ull*)(P.u + pp * 16384 + b * 512) + tid);
        float f2[2]; __builtin_memcpy(f2, &v, 8);
        unsigned pk = (unsigned)f2b(f2[0] * rZ) | ((unsigned)f2b(f2[1] * rZ) << 16);
        *(unsigned*)(P.mlpin + ((size_t)(t - 1) * 32 + b) * 1024 + 512 + tid * 2) = pk;
        DRAIN;
      }
      __syncthreads();
      if (tid == 0) astw(P.arrY + bb * 4, tv);
    } else if (bb < 224){
      astf(P.u + p * 16384 + (bb - 160) * 256 + tid, 0.f);   // clear u[p] for S34(t)
      DRAIN; __syncthreads();
      if (tid == 0) astw(P.arrY + bb * 4, tv);
    } else if (bb == 224){
      if (tid < 32) astf(P.Zb + p * 32 + tid, 0.f);          // clear Zb[p]
      DRAIN; __syncthreads();
      if (tid == 0) astw(P.arrY + bb * 4, tv);
    } else {
      if (tid == 0) astw(P.arrY + bb * 4, tv);
    }
    // ---- arrY wait (all 256 blocks) ----
    if (tid < 64){
      int spin = 0;
      for (;;){
        unsigned f0 = aldw(P.arrY + (tid      ) * 4);
        unsigned f1 = aldw(P.arrY + (tid +  64) * 4);
        unsigned f2 = aldw(P.arrY + (tid + 128) * 4);
        unsigned f3 = aldw(P.arrY + (tid + 192) * 4);
        if (__all((f0 >= tv) & (f1 >= tv) & (f2 >= tv) & (f3 >= tv))) break;
        if (++spin > SPINCAP) break;
        __builtin_amdgcn_s_sleep(1);
      }
    }
    __syncthreads();
    // ---- S34: scores + softmax + context partials (atomicAdd u[p], Zb[p]) ----
    {
      ull v = aldu((const ull*)(P.Xh1f + p * 16384 + b_att * 512) + tid);
      float f2[2]; __builtin_memcpy(f2, &v, 8);
      h1_s[tid * 2] = f2[0]; h1_s[tid * 2 + 1] = f2[1];
    }
    __syncthreads();
    {
      const int ti_l = tid >> 1, half = tid & 1;
      float s = 0.f;
      const unsigned swz = (unsigned)(ti_l & 7) << 4;
      for (int h8 = half * 256; h8 < half * 256 + 256; h8 += 8){
        unsigned byteoff = ((unsigned)(ti_l * 512 + h8) * 2u) ^ swz;
        s16x8 ev = *(const s16x8*)((const char*)enc_s + byteoff);
        #pragma unroll
        for (int e = 0; e < 8; ++e) s += b2f((unsigned short)ev[e]) * h1_s[h8 + e];
      }
      s += __shfl_xor(s, 1);
      if (half == 0) w_s[ti_l] = expf(s);       // no max-shift: |s| << 88
    }
    __syncthreads();
    {
      if (tid < 128){
        float z = w_s[tid];
        #pragma unroll
        for (int off = 1; off < 64; off <<= 1) z += __shfl_xor(z, off);
        if ((tid & 63) == 0) zred[tid >> 6] = z;
      }
      float a0 = 0.f, a1 = 0.f;
      const int hc = tid * 2;
      for (int ti = 0; ti < 128; ++ti){
        const float wvv = w_s[ti];
        unsigned byteoff = ((unsigned)(ti * 1024 + hc * 2)) ^ ((unsigned)(ti & 7) << 4);
        unsigned pk = *(const unsigned*)((const char*)enc_s + byteoff);
        a0 += wvv * b2f((unsigned short)(pk & 0xffffu));
        a1 += wvv * b2f((unsigned short)(pk >> 16));
      }
      unsafeAtomicAdd(P.u + p * 16384 + b_att * 512 + hc, a0);
      unsafeAtomicAdd(P.u + p * 16384 + b_att * 512 + hc + 1, a1);
      __syncthreads();
      if (tid == 0) unsafeAtomicAdd(P.Zb + p * 32 + b_att, zred[0] + zred[1]);
      DRAIN; __syncthreads();
      if (tid == 0) astw(P.marr + (b_att * 8 + tc) * 4, tv);
    }
  }
  // ---- tail: att_c(t=256), p=0 ----
  if (bb >= 128 && bb < 160){
    const int b = bb - 128;
    if (tid < 64){
      const unsigned want = (unsigned)T_;
      int spin = 0;
      for (;;){
        unsigned f = (tid < 8) ? aldw(P.marr + (b * 8 + tid) * 4) : want;
        if (__all(f >= want)) break;
        if (++spin > SPINCAP) break;
        __builtin_amdgcn_s_sleep(1);
      }
    }
    __syncthreads();
    const float rZ = 1.f / aldf(P.Zb + 0 * 32 + b);
    ull v = aldu((const ull*)(P.u + 0 * 16384 + b * 512) + tid);
    float f2[2]; __builtin_memcpy(f2, &v, 8);
    unsigned pk = (unsigned)f2b(f2[0] * rZ) | ((unsigned)f2b(f2[1] * rZ) << 16);
    *(unsigned*)(P.mlpin + ((size_t)256 * 32 + b) * 1024 + 512 + tid * 2) = pk;
  }
}

// ------------------------------------------------------------------
// B1: tanhv = tanh(mlpin @ W1^T + b1)   M=8224 N=512 K=1024, bf16 MFMA
__global__ __launch_bounds__(256) void kB1(Ptrs P){
  const int wid = blockIdx.x * 4 + (threadIdx.x >> 6);
  if (wid >= 129 * 8) return;
  const int mt = wid >> 3, nt = wid & 7;
  const int l = threadIdx.x & 63, lr = l & 15, lk = l >> 4;
  const int mr = mt * 64, nc = nt * 64;
  f32x4 acc[4][4] = {};
  for (int k0 = 0; k0 < 1024; k0 += 32){
    s16x8 af[4], bfm[4];
    #pragma unroll
    for (int f = 0; f < 4; ++f){
      int row = mr + f * 16 + lr; if (row > NROW_ - 1) row = NROW_ - 1;
      af[f] = *(const s16x8*)(P.mlpin + (size_t)row * 1024 + k0 + lk * 8);
      int col = nc + f * 16 + lr;
      bfm[f] = *(const s16x8*)(P.W1b + (size_t)col * 1024 + k0 + lk * 8);
    }
    #pragma unroll
    for (int fi = 0; fi < 4; ++fi)
      #pragma unroll
      for (int fj = 0; fj < 4; ++fj)
        acc[fi][fj] = __builtin_amdgcn_mfma_f32_16x16x32_bf16(af[fi], bfm[fj], acc[fi][fj], 0, 0, 0);
  }
  #pragma unroll
  for (int fi = 0; fi < 4; ++fi){
    #pragma unroll
    for (int jj = 0; jj < 4; ++jj){
      int m = mr + fi * 16 + lk * 4 + jj;
      if (m >= NROW_) continue;
      #pragma unroll
      for (int fj = 0; fj < 4; ++fj){
        int n = nc + fj * 16 + lr;
        P.tanhv[(size_t)m * 512 + n] = f2b(tanhf(acc[fi][fj][jj] + P.b1[n]));
      }
    }
  }
}

// B2: logits = tanhv @ W2^T + b2, fused exp-rowsum.  M=8224 N=10000 K=512
__global__ __launch_bounds__(256) void kB2(Ptrs P){
  const int wid = blockIdx.x * 4 + (threadIdx.x >> 6);
  if (wid >= 129 * 157) return;
  const int mt = wid / 157, nt = wid % 157;
  const int l = threadIdx.x & 63, lr = l & 15, lk = l >> 4;
  const int mr = mt * 64, nc = nt * 64;
  f32x4 acc[4][4] = {};
  for (int k0 = 0; k0 < 512; k0 += 32){
    s16x8 af[4], bfm[4];
    #pragma unroll
    for (int f = 0; f < 4; ++f){
      int row = mr + f * 16 + lr; if (row > NROW_ - 1) row = NROW_ - 1;
      af[f] = *(const s16x8*)(P.tanhv + (size_t)row * 512 + k0 + lk * 8);
      int col = nc + f * 16 + lr; if (col > V_ - 1) col = V_ - 1;
      bfm[f] = *(const s16x8*)(P.W2b + (size_t)col * 512 + k0 + lk * 8);
    }
    #pragma unroll
    for (int fi = 0; fi < 4; ++fi)
      #pragma unroll
      for (int fj = 0; fj < 4; ++fj)
        acc[fi][fj] = __builtin_amdgcn_mfma_f32_16x16x32_bf16(af[fi], bfm[fj], acc[fi][fj], 0, 0, 0);
  }
  #pragma unroll
  for (int fi = 0; fi < 4; ++fi){
    #pragma unroll
    for (int jj = 0; jj < 4; ++jj){
      const int m = mr + fi * 16 + lk * 4 + jj;
      float s = 0.f;
      #pragma unroll
      for (int fj = 0; fj < 4; ++fj){
        int n = nc + fj * 16 + lr;
        if (n < V_) s += expf(acc[fi][fj][jj] + P.b2[n]);
      }
      s += __shfl_xor(s, 1); s += __shfl_xor(s, 2);
      s += __shfl_xor(s, 4); s += __shfl_xor(s, 8);
      if (lr == 0 && m < NROW_) unsafeAtomicAdd(P.rowsum + m, s);
    }
  }
}

// label logit per row (one wave per row)
__global__ __launch_bounds__(256) void kL1(Ptrs P){
  const int wid = blockIdx.x * 4 + (threadIdx.x >> 6);
  if (wid >= NROW_) return;
  const int l = threadIdx.x & 63;
  const int t = wid >> 5, b = wid & 31;
  const int lab = (t < TO_) ? P.padded[b * TO_ + t] : 2;   // EOS=2
  float s = 0.f;
  s16x8 av = *(const s16x8*)(P.tanhv + (size_t)wid * 512 + l * 8);
  s16x8 wv = *(const s16x8*)(P.W2b + (size_t)lab * 512 + l * 8);
  #pragma unroll
  for (int e = 0; e < 8; ++e) s += b2f((unsigned short)av[e]) * b2f((unsigned short)wv[e]);
  #pragma unroll
  for (int off = 1; off < 64; off <<= 1) s += __shfl_xor(s, off);
  if (l == 0) P.lablog[wid] = s + P.b2[lab];
}

// final masked-NLL reduction
__global__ __launch_bounds__(512) void kL2(Ptrs P){
  __shared__ float ssum[8], scnt[8];
  const int tid = threadIdx.x;
  float sum = 0.f, cnt = 0.f;
  for (int rr = tid; rr < NROW_; rr += 512){
    int t = rr >> 5, b = rr & 31;
    int lab = (t < TO_) ? P.padded[b * TO_ + t] : 2;
    if (lab != 0){ sum += logf(P.rowsum[rr]) - P.lablog[rr]; cnt += 1.f; }
  }
  #pragma unroll
  for (int off = 1; off < 64; off <<= 1){ sum += __shfl_xor(sum, off); cnt += __shfl_xor(cnt, off); }
  if ((tid & 63) == 0){ ssum[tid >> 6] = sum; scnt[tid >> 6] = cnt; }
  __syncthreads();
  if (tid == 0){
    float S = 0.f, C = 0.f;
    for (int i = 0; i < 8; ++i){ S += ssum[i]; C += scnt[i]; }
    P.out[0] = S / fmaxf(C, 1.f);
  }
}

// ------------------------------------------------------------------
extern "C" void kernel_launch(void* const* d_in, const int* in_sizes, int n_in,
                              void* d_out, int out_size, void* d_ws, size_t ws_size,
                              hipStream_t stream){
  (void)in_sizes; (void)n_in; (void)out_size; (void)ws_size;
  Ptrs P;
  P.padded = (const int*)d_in[0];
  P.enc    = (const float*)d_in[1];
  P.emb    = (const float*)d_in[2];
  P.Wih0 = (const float*)d_in[3];  P.Whh0 = (const float*)d_in[4];
  P.bih0 = (const float*)d_in[5];  P.bhh0 = (const float*)d_in[6];
  P.Wih1 = (const float*)d_in[7];  P.Whh1 = (const float*)d_in[8];
  P.bih1 = (const float*)d_in[9];  P.bhh1 = (const float*)d_in[10];
  P.W1 = (const float*)d_in[11];   P.b1 = (const float*)d_in[12];
  P.W2 = (const float*)d_in[13];   P.b2 = (const float*)d_in[14];
  P.out = (float*)d_out;

  char* w = (char*)d_ws;
  size_t off = 0;
  auto take = [&](size_t bytes) -> void* {
    void* ptr = (void*)(w + off);
    off += (bytes + 255) & ~(size_t)255;
    return ptr;
  };
  P.mlpin  = (unsigned short*)take((size_t)T_ * B_ * 1024 * 2);   // 16.84 MB
  P.embt   = (unsigned short*)take((size_t)T_ * B_ * 512 * 2);    // 8.42 MB
  P.tanhv  = P.embt;                                              // overlay (post-kA)
  P.W0c    = (unsigned short*)take((size_t)2048 * 1536 * 2);      // 6.29 MB
  P.W1c    = (unsigned short*)take((size_t)2048 * 1024 * 2);      // 4.19 MB
  P.W2b    = P.W0c;                                               // overlay (post-kA)
  P.W1b    = (unsigned short*)take((size_t)512 * 1024 * 2);       // 1.05 MB
  P.bias0c = (float*)take(2048 * 4);
  P.bias1c = (float*)take(2048 * 4);
  P.u      = (float*)take(2 * 32 * 512 * 4);
  P.Zb     = (float*)take(2 * 32 * 4);
  P.Xh0    = (unsigned short*)take(2 * 32 * 512 * 2);
  P.Xh1    = (unsigned short*)take(2 * 32 * 512 * 2);
  P.Xh1f   = (float*)take(2 * 32 * 512 * 4);
  P.arrX   = (unsigned*)take(128 * 4 * 4);
  P.arrY   = (unsigned*)take(256 * 4 * 4);
  P.marr   = (unsigned*)take(256 * 4 * 4);
  P.dX     = (unsigned*)take(128 * 4 * 4);
  P.dY     = (unsigned*)take(256 * 4 * 4);
  P.dM     = (unsigned*)take(256 * 4 * 4);
  P.ibar   = (unsigned*)take(256 * 4 * 4);
  P.rowsum = (float*)take(NROW_ * 4);
  P.lablog = (float*)take(NROW_ * 4);

  kprep<<<dim3(2048), dim3(256), 0, stream>>>(P);
  void* args[] = { (void*)&P };
  hipLaunchCooperativeKernel(kA, dim3(NB_), dim3(256), args, 0, stream);
  kprep2<<<dim3(1024), dim3(256), 0, stream>>>(P);
  kB1<<<dim3(258),  dim3(256), 0, stream>>>(P);
  kB2<<<dim3(5064), dim3(256), 0, stream>>>(P);
  kL1<<<dim3(2056), dim3(256), 0, stream>>>(P);
  kL2<<<dim3(1),    dim3(512), 0, stream>>>(P);
}

// Round 10
// 8725.784 us; speedup vs baseline: 1.0326x; 1.0326x over previous
//
#include <hip/hip_runtime.h>
#include <hip/hip_bf16.h>

// Problem constants
#define B_    32
#define TO_   256
#define T_    257        // To+1 decode steps
#define H_    512
#define V_    10000
#define TI_   1024
#define NROW_ 8224       // T_*B_
#define NB_   256        // blocks in cooperative kernel
#define SPINCAP 150000

using f32x4 = __attribute__((ext_vector_type(4))) float;
using s16x8 = __attribute__((ext_vector_type(8))) short;
typedef unsigned long long ull;

// Tagged word: lo32 = payload (2xbf16 or f32), hi32 = step tag. One 8B
// relaxed sc1 store publishes data+freshness atomically; consumers poll the
// data words directly (flag read IS data read -> 1 L3 RT per handoff).
struct Ptrs {
  const int* padded;
  const float* enc;
  const float* emb;
  const float *Wih0, *Whh0, *bih0, *bhh0;
  const float *Wih1, *Whh1, *bih1, *bhh1;
  const float *W1, *b1, *W2, *b2;
  float* out;
  // workspace
  unsigned short *mlpin;   // [257][32][1024] bf16  (=[h1 | att_c])
  unsigned short *embt;    // [257][32][512] bf16; tanhv overlays after kA
  unsigned short *tanhv;   // [8224][512] bf16 (== embt region)
  unsigned short *W0c;     // [2048][1536] bf16 rows g'=j*4+q = [Wih0 | Whh0]; W2b overlays
  unsigned short *W1c;     // [2048][1024] bf16 rows g'=j*4+q = [Wih1 | Whh1]
  unsigned short *W1b;     // [512][1024] bf16
  unsigned short *W2b;     // [10000][512] bf16 (== W0c region, kprep2)
  float *bias0c, *bias1c;  // [2048] combined biases, gate-interleaved
  // tagged ping-pong state
  ull *h0T;                // [2][32][256] {2xbf16 | tag} j-pair units
  ull *h1T;                // [2][32][256] {2xbf16 | tag}
  ull *h1fT;               // [2][32][512] {f32 | tag}
  ull *upT;                // [2][32][8][512] {f32 partial | tag}
  ull *zpT;                // [2][32][8] {f32 z-partial | tag}
  ull *atT;                // [2][32][256] {2xbf16 attc | tag}
  float *rowsum;           // [8224]
  float *lablog;           // [8224]
};

__device__ __forceinline__ unsigned short f2b(float f){
  __hip_bfloat16 h = __float2bfloat16(f);
  unsigned short r; __builtin_memcpy(&r, &h, 2); return r;
}
__device__ __forceinline__ float b2f(unsigned short u){
  unsigned v = ((unsigned)u) << 16; float f; __builtin_memcpy(&f, &v, 4); return f;
}
__device__ __forceinline__ float sigf(float x){ return 1.f / (1.f + expf(-x)); }

// ---- agent-scope (sc1, L3) relaxed atomics ----
__device__ __forceinline__ ull aldu(const ull* p){
  return __hip_atomic_load(p, __ATOMIC_RELAXED, __HIP_MEMORY_SCOPE_AGENT);
}
__device__ __forceinline__ void astu(ull* p, ull v){
  __hip_atomic_store(p, v, __ATOMIC_RELAXED, __HIP_MEMORY_SCOPE_AGENT);
}
#define DRAIN asm volatile("s_waitcnt vmcnt(0)" ::: "memory")
#define TAG(v) ((unsigned)((v) >> 32))
#define LO(v)  ((unsigned)(v))

// ------------------------------------------------------------------
__global__ __launch_bounds__(256) void kprep(Ptrs P){
  const int stride = gridDim.x * blockDim.x;
  const int i0 = blockIdx.x * blockDim.x + threadIdx.x;
  for (int i = i0; i < 2 * 32 * 256; i += stride){ P.h0T[i] = 0; P.h1T[i] = 0; P.atT[i] = 0; }
  for (int i = i0; i < 2 * 32 * 512; i += stride) P.h1fT[i] = 0;
  for (int i = i0; i < 2 * 32 * 8 * 512; i += stride) P.upT[i] = 0;
  for (int i = i0; i < 2 * 32 * 8; i += stride) P.zpT[i] = 0;
  for (int i = i0; i < T_ * B_ * 512; i += stride){
    int k = i & 511, tb = i >> 9, b = tb & 31, t = tb >> 5;
    int tok = (t == 0) ? 1 : P.padded[b * TO_ + (t - 1)];
    P.embt[i] = f2b(P.emb[(size_t)tok * 512 + k]);
  }
  for (int i = i0; i < 2048 * 1536; i += stride){
    int k = i % 1536, gp = i / 1536;
    int j = gp >> 2, q = gp & 3, g = q * 512 + j;
    float v = (k < 1024) ? P.Wih0[(size_t)g * 1024 + k] : P.Whh0[(size_t)g * 512 + (k - 1024)];
    P.W0c[i] = f2b(v);
  }
  for (int i = i0; i < 2048 * 1024; i += stride){
    int k = i & 1023, gp = i >> 10;
    int j = gp >> 2, q = gp & 3, g = q * 512 + j;
    float v = (k < 512) ? P.Wih1[(size_t)g * 512 + k] : P.Whh1[(size_t)g * 512 + (k - 512)];
    P.W1c[i] = f2b(v);
  }
  for (int i = i0; i < 2048; i += stride){
    int j = i >> 2, q = i & 3, g = q * 512 + j;
    P.bias0c[i] = P.bih0[g] + P.bhh0[g];
    P.bias1c[i] = P.bih1[g] + P.bhh1[g];
  }
  for (int i = i0; i < 512 * 1024; i += stride) P.W1b[i] = f2b(P.W1[i]);
  for (int i = i0; i < NROW_; i += stride) P.rowsum[i] = 0.f;
}

__global__ __launch_bounds__(256) void kprep2(Ptrs P){
  const int stride = gridDim.x * blockDim.x;
  const int i0 = blockIdx.x * blockDim.x + threadIdx.x;
  for (int i = i0; i < V_ * 512; i += stride) P.W2b[i] = f2b(P.W2[i]);
}

// ------------------------------------------------------------------
// Phase A. Per step t (tv = t+1), poll-on-tagged-data only:
//  GEMM (0-127):  S1 {e-seg + h0prev-seg unpolled; poll atT(t-1); att-seg} ->
//                 h0T tagged. S2 {h1prev-seg unpolled; poll h0T(t); h0-seg} ->
//                 h1T+mlpin, DRAIN, h1fT tagged (release edge).
//  all 256:       S34 {poll h1fT(t); scores; softmax; context} -> upT+zpT tagged.
//  reducers (128-159, b=bb-128): poll upT/zpT(t) -> atT tagged + mlpin att_c(t).
__global__ __launch_bounds__(256, 1) void kA(Ptrs P){
  __shared__ __align__(16) unsigned short enc_s[128 * 512]; // 128 KB, XOR-swizzled
  __shared__ float h1_s[512];
  __shared__ float w_s[128];
  __shared__ float gate_s[2][32][17];
  __shared__ float h_s[32][4];
  __shared__ float zred[2];
  const int bb = blockIdx.x, tid = threadIdx.x;
  const int b_att = bb >> 3, tc = bb & 7;

  { // stage encoder slice -> LDS bf16, byte^((row&7)<<4) swizzle
    const float* ep = P.enc + ((size_t)b_att * TI_ + (size_t)tc * 128) * H_;
    for (int idx = tid; idx < 128 * 512; idx += 256){
      int row = idx >> 9;
      unsigned byteoff = ((unsigned)idx * 2u) ^ ((unsigned)(row & 7) << 4);
      enc_s[byteoff >> 1] = f2b(ep[idx]);
    }
  }
  // no grid barrier needed: kprep (stream-ordered) zeroed all tags.

  const int wv = tid >> 6, l = tid & 63, lr = l & 15, lk = l >> 4;
  const int bh = wv & 1, kh = wv >> 1;          // batch-half, K-half
  const int batch = bh * 16 + lr;
  const int eidx = tid - 128, eb = eidx >> 2, ejl = eidx & 3;
  const bool isGemm = bb < 128;
  const bool isRed = (bb >= 128 && bb < 160);
  const int rb = bb - 128;
  float c0r = 0.f, c1r = 0.f;

  for (int t = 0; t < T_; ++t){
    const int p = t & 1, pp = p ^ 1;
    const unsigned tv = (unsigned)t + 1u;
    if (isGemm){
      const unsigned short* Brow = P.W0c + (size_t)(bb * 16 + lr) * 1536;
      const unsigned short* Erow = P.embt + ((size_t)t * 32 + batch) * 512;
      f32x4 acc = {0.f, 0.f, 0.f, 0.f};
      // ---- S1 e-seg (static data) ----
      #pragma unroll
      for (int ks = 0; ks < 8; ++ks){
        const int kb = (kh * 8 + ks) * 32 + lk * 8;
        s16x8 a = *(const s16x8*)(Erow + kb);
        s16x8 b = *(const s16x8*)(Brow + kb);
        acc = __builtin_amdgcn_mfma_f32_16x16x32_bf16(a, b, acc, 0, 0, 0);
      }
      // ---- S1 h0prev-seg (h0T[pp], transitively fresh, unpolled) ----
      {
        const ull* H = P.h0T + (size_t)(pp * 32 + batch) * 256;
        #pragma unroll
        for (int ks = 0; ks < 8; ++ks){
          const int u = (kh * 8 + ks) * 16 + lk * 4;
          ull d0 = aldu(H + u), d1 = aldu(H + u + 1), d2 = aldu(H + u + 2), d3 = aldu(H + u + 3);
          s16x8 a; unsigned* ap = (unsigned*)&a;
          ap[0] = LO(d0); ap[1] = LO(d1); ap[2] = LO(d2); ap[3] = LO(d3);
          s16x8 b = *(const s16x8*)(Brow + 1024 + (kh * 8 + ks) * 32 + lk * 8);
          acc = __builtin_amdgcn_mfma_f32_16x16x32_bf16(a, b, acc, 0, 0, 0);
        }
      }
      // ---- poll atT[pp] (attc(t-1), tag >= t) ----
      ull av[32];
      {
        const ull* A = P.atT + (size_t)(pp * 32 + batch) * 256;
        const unsigned want = (unsigned)t;
        int spin = 0;
        for (;;){
          bool ok = true;
          #pragma unroll
          for (int ks = 0; ks < 8; ++ks){
            const int u = (kh * 8 + ks) * 16 + lk * 4;
            #pragma unroll
            for (int q = 0; q < 4; ++q){
              av[ks * 4 + q] = aldu(A + u + q);
              ok &= (TAG(av[ks * 4 + q]) >= want);
            }
          }
          if (__all(ok)) break;
          if (++spin > SPINCAP) break;
          __builtin_amdgcn_s_sleep(1);
        }
      }
      // ---- S1 att-seg ----
      #pragma unroll
      for (int ks = 0; ks < 8; ++ks){
        s16x8 a; unsigned* ap = (unsigned*)&a;
        ap[0] = LO(av[ks * 4 + 0]); ap[1] = LO(av[ks * 4 + 1]);
        ap[2] = LO(av[ks * 4 + 2]); ap[3] = LO(av[ks * 4 + 3]);
        s16x8 b = *(const s16x8*)(Brow + 512 + (kh * 8 + ks) * 32 + lk * 8);
        acc = __builtin_amdgcn_mfma_f32_16x16x32_bf16(a, b, acc, 0, 0, 0);
      }
      #pragma unroll
      for (int j = 0; j < 4; ++j) gate_s[kh][bh * 16 + lk * 4 + j][lr] = acc[j];
      __syncthreads();
      if (tid >= 128){
        const float* bs = P.bias0c + bb * 16 + ejl * 4;
        float ii = sigf (gate_s[0][eb][ejl * 4 + 0] + gate_s[1][eb][ejl * 4 + 0] + bs[0]);
        float ff = sigf (gate_s[0][eb][ejl * 4 + 1] + gate_s[1][eb][ejl * 4 + 1] + bs[1]);
        float gg = tanhf(gate_s[0][eb][ejl * 4 + 2] + gate_s[1][eb][ejl * 4 + 2] + bs[2]);
        float oo = sigf (gate_s[0][eb][ejl * 4 + 3] + gate_s[1][eb][ejl * 4 + 3] + bs[3]);
        float cn = ff * c0r + ii * gg; c0r = cn;
        h_s[eb][ejl] = oo * tanhf(cn);
      }
      __syncthreads();
      if (tid < 32){   // publish tagged h0 (self-tagged; no drain, no flag)
        unsigned lo0 = (unsigned)f2b(h_s[tid][0]) | ((unsigned)f2b(h_s[tid][1]) << 16);
        unsigned lo1 = (unsigned)f2b(h_s[tid][2]) | ((unsigned)f2b(h_s[tid][3]) << 16);
        ull* D = P.h0T + (size_t)(p * 32 + tid) * 256 + bb * 2;
        astu(D,     (ull)lo0 | ((ull)tv << 32));
        astu(D + 1, (ull)lo1 | ((ull)tv << 32));
      }
      // ---- S2: h1prev-seg (h1T[pp] unpolled) ----
      const unsigned short* Brow1 = P.W1c + (size_t)(bb * 16 + lr) * 1024;
      f32x4 acc2 = {0.f, 0.f, 0.f, 0.f};
      {
        const ull* H = P.h1T + (size_t)(pp * 32 + batch) * 256;
        #pragma unroll
        for (int ks = 0; ks < 8; ++ks){
          const int u = (kh * 8 + ks) * 16 + lk * 4;
          ull d0 = aldu(H + u), d1 = aldu(H + u + 1), d2 = aldu(H + u + 2), d3 = aldu(H + u + 3);
          s16x8 a; unsigned* ap = (unsigned*)&a;
          ap[0] = LO(d0); ap[1] = LO(d1); ap[2] = LO(d2); ap[3] = LO(d3);
          s16x8 b = *(const s16x8*)(Brow1 + 512 + (kh * 8 + ks) * 32 + lk * 8);
          acc2 = __builtin_amdgcn_mfma_f32_16x16x32_bf16(a, b, acc2, 0, 0, 0);
        }
      }
      // ---- poll h0T[p] (tag >= tv) ----
      {
        const ull* H = P.h0T + (size_t)(p * 32 + batch) * 256;
        int spin = 0;
        for (;;){
          bool ok = true;
          #pragma unroll
          for (int ks = 0; ks < 8; ++ks){
            const int u = (kh * 8 + ks) * 16 + lk * 4;
            #pragma unroll
            for (int q = 0; q < 4; ++q){
              av[ks * 4 + q] = aldu(H + u + q);
              ok &= (TAG(av[ks * 4 + q]) >= tv);
            }
          }
          if (__all(ok)) break;
          if (++spin > SPINCAP) break;
          __builtin_amdgcn_s_sleep(1);
        }
      }
      #pragma unroll
      for (int ks = 0; ks < 8; ++ks){
        s16x8 a; unsigned* ap = (unsigned*)&a;
        ap[0] = LO(av[ks * 4 + 0]); ap[1] = LO(av[ks * 4 + 1]);
        ap[2] = LO(av[ks * 4 + 2]); ap[3] = LO(av[ks * 4 + 3]);
        s16x8 b = *(const s16x8*)(Brow1 + (kh * 8 + ks) * 32 + lk * 8);
        acc2 = __builtin_amdgcn_mfma_f32_16x16x32_bf16(a, b, acc2, 0, 0, 0);
      }
      #pragma unroll
      for (int j = 0; j < 4; ++j) gate_s[kh][bh * 16 + lk * 4 + j][lr] = acc2[j];
      __syncthreads();
      if (tid >= 128){
        const float* bs = P.bias1c + bb * 16 + ejl * 4;
        float ii = sigf (gate_s[0][eb][ejl * 4 + 0] + gate_s[1][eb][ejl * 4 + 0] + bs[0]);
        float ff = sigf (gate_s[0][eb][ejl * 4 + 1] + gate_s[1][eb][ejl * 4 + 1] + bs[1]);
        float gg = tanhf(gate_s[0][eb][ejl * 4 + 2] + gate_s[1][eb][ejl * 4 + 2] + bs[2]);
        float oo = sigf (gate_s[0][eb][ejl * 4 + 3] + gate_s[1][eb][ejl * 4 + 3] + bs[3]);
        float cn = ff * c1r + ii * gg; c1r = cn;
        h_s[eb][ejl] = oo * tanhf(cn);
      }
      __syncthreads();
      if (tid < 32){
        unsigned lo0 = (unsigned)f2b(h_s[tid][0]) | ((unsigned)f2b(h_s[tid][1]) << 16);
        unsigned lo1 = (unsigned)f2b(h_s[tid][2]) | ((unsigned)f2b(h_s[tid][3]) << 16);
        ull* D = P.h1T + (size_t)(p * 32 + tid) * 256 + bb * 2;
        astu(D,     (ull)lo0 | ((ull)tv << 32));
        astu(D + 1, (ull)lo1 | ((ull)tv << 32));
        ull hv = (ull)lo0 | ((ull)lo1 << 32);
        *(ull*)(P.mlpin + ((size_t)t * 32 + tid) * 1024 + bb * 4) = hv;
        DRAIN;  // release edge: h1T/mlpin visible before h1fT tags
        ull* F = P.h1fT + (size_t)(p * 32 + tid) * 512 + bb * 4;
        #pragma unroll
        for (int jl = 0; jl < 4; ++jl)
          astu(F + jl, (ull)__float_as_uint(h_s[tid][jl]) | ((ull)tv << 32));
      }
    }
    // ================= S34 (all 256 blocks) =================
    {
      const ull* Hf = P.h1fT + (size_t)(p * 32 + b_att) * 512 + tid * 2;
      ull v0 = 0, v1 = 0;
      int spin = 0;
      for (;;){
        v0 = aldu(Hf); v1 = aldu(Hf + 1);
        bool ok = (TAG(v0) >= tv) & (TAG(v1) >= tv);
        if (__all(ok)) break;
        if (++spin > SPINCAP) break;
        __builtin_amdgcn_s_sleep(1);
      }
      h1_s[tid * 2]     = __uint_as_float(LO(v0));
      h1_s[tid * 2 + 1] = __uint_as_float(LO(v1));
    }
    __syncthreads();
    {
      const int ti_l = tid >> 1, half = tid & 1;
      float s = 0.f;
      const unsigned swz = (unsigned)(ti_l & 7) << 4;
      for (int h8 = half * 256; h8 < half * 256 + 256; h8 += 8){
        unsigned byteoff = ((unsigned)(ti_l * 512 + h8) * 2u) ^ swz;
        s16x8 ev = *(const s16x8*)((const char*)enc_s + byteoff);
        #pragma unroll
        for (int e = 0; e < 8; ++e) s += b2f((unsigned short)ev[e]) * h1_s[h8 + e];
      }
      s += __shfl_xor(s, 1);
      if (half == 0) w_s[ti_l] = expf(s);       // no max-shift: |s| << 88
    }
    __syncthreads();
    {
      if (tid < 128){
        float z = w_s[tid];
        #pragma unroll
        for (int off = 1; off < 64; off <<= 1) z += __shfl_xor(z, off);
        if ((tid & 63) == 0) zred[tid >> 6] = z;
      }
      float a0 = 0.f, a1 = 0.f;
      const int hc = tid * 2;
      for (int ti = 0; ti < 128; ++ti){
        const float wvv = w_s[ti];
        unsigned byteoff = ((unsigned)(ti * 1024 + hc * 2)) ^ ((unsigned)(ti & 7) << 4);
        unsigned pk = *(const unsigned*)((const char*)enc_s + byteoff);
        a0 += wvv * b2f((unsigned short)(pk & 0xffffu));
        a1 += wvv * b2f((unsigned short)(pk >> 16));
      }
      ull* U = P.upT + ((size_t)(p * 32 + b_att) * 8 + tc) * 512 + hc;
      astu(U,     (ull)__float_as_uint(a0) | ((ull)tv << 32));
      astu(U + 1, (ull)__float_as_uint(a1) | ((ull)tv << 32));
      __syncthreads();
      if (tid == 0)
        astu(P.zpT + (size_t)(p * 32 + b_att) * 8 + tc,
             (ull)__float_as_uint(zred[0] + zred[1]) | ((ull)tv << 32));
    }
    // ================= reducer (blocks 128-159): publish attc(t) =================
    if (isRed){
      const ull* ub = P.upT + ((size_t)(p * 32 + rb) * 8) * 512 + tid * 2;
      const ull* zb = P.zpT + (size_t)(p * 32 + rb) * 8;
      ull u0[8], u1[8], zv[8];
      int spin = 0;
      for (;;){
        bool ok = true;
        #pragma unroll
        for (int c = 0; c < 8; ++c){
          u0[c] = aldu(ub + c * 512);
          u1[c] = aldu(ub + c * 512 + 1);
          zv[c] = aldu(zb + c);
          ok &= (TAG(u0[c]) >= tv) & (TAG(u1[c]) >= tv) & (TAG(zv[c]) >= tv);
        }
        if (__all(ok)) break;
        if (++spin > SPINCAP) break;
        __builtin_amdgcn_s_sleep(1);
      }
      float s0 = 0.f, s1 = 0.f, zs = 0.f;
      #pragma unroll
      for (int c = 0; c < 8; ++c){
        s0 += __uint_as_float(LO(u0[c]));
        s1 += __uint_as_float(LO(u1[c]));
        zs += __uint_as_float(LO(zv[c]));
      }
      const float rZ = 1.f / zs;
      unsigned pk = (unsigned)f2b(s0 * rZ) | ((unsigned)f2b(s1 * rZ) << 16);
      astu(P.atT + (size_t)(p * 32 + rb) * 256 + tid, (ull)pk | ((ull)tv << 32));
      *(unsigned*)(P.mlpin + ((size_t)t * 32 + rb) * 1024 + 512 + tid * 2) = pk;
    }
  }
}

// ------------------------------------------------------------------
// B1: tanhv = tanh(mlpin @ W1^T + b1)   M=8224 N=512 K=1024, bf16 MFMA
__global__ __launch_bounds__(256) void kB1(Ptrs P){
  const int wid = blockIdx.x * 4 + (threadIdx.x >> 6);
  if (wid >= 129 * 8) return;
  const int mt = wid >> 3, nt = wid & 7;
  const int l = threadIdx.x & 63, lr = l & 15, lk = l >> 4;
  const int mr = mt * 64, nc = nt * 64;
  f32x4 acc[4][4] = {};
  for (int k0 = 0; k0 < 1024; k0 += 32){
    s16x8 af[4], bfm[4];
    #pragma unroll
    for (int f = 0; f < 4; ++f){
      int row = mr + f * 16 + lr; if (row > NROW_ - 1) row = NROW_ - 1;
      af[f] = *(const s16x8*)(P.mlpin + (size_t)row * 1024 + k0 + lk * 8);
      int col = nc + f * 16 + lr;
      bfm[f] = *(const s16x8*)(P.W1b + (size_t)col * 1024 + k0 + lk * 8);
    }
    #pragma unroll
    for (int fi = 0; fi < 4; ++fi)
      #pragma unroll
      for (int fj = 0; fj < 4; ++fj)
        acc[fi][fj] = __builtin_amdgcn_mfma_f32_16x16x32_bf16(af[fi], bfm[fj], acc[fi][fj], 0, 0, 0);
  }
  #pragma unroll
  for (int fi = 0; fi < 4; ++fi){
    #pragma unroll
    for (int jj = 0; jj < 4; ++jj){
      int m = mr + fi * 16 + lk * 4 + jj;
      if (m >= NROW_) continue;
      #pragma unroll
      for (int fj = 0; fj < 4; ++fj){
        int n = nc + fj * 16 + lr;
        P.tanhv[(size_t)m * 512 + n] = f2b(tanhf(acc[fi][fj][jj] + P.b1[n]));
      }
    }
  }
}

// B2: logits = tanhv @ W2^T + b2, fused exp-rowsum.  M=8224 N=10000 K=512
__global__ __launch_bounds__(256) void kB2(Ptrs P){
  const int wid = blockIdx.x * 4 + (threadIdx.x >> 6);
  if (wid >= 129 * 157) return;
  const int mt = wid / 157, nt = wid % 157;
  const int l = threadIdx.x & 63, lr = l & 15, lk = l >> 4;
  const int mr = mt * 64, nc = nt * 64;
  f32x4 acc[4][4] = {};
  for (int k0 = 0; k0 < 512; k0 += 32){
    s16x8 af[4], bfm[4];
    #pragma unroll
    for (int f = 0; f < 4; ++f){
      int row = mr + f * 16 + lr; if (row > NROW_ - 1) row = NROW_ - 1;
      af[f] = *(const s16x8*)(P.tanhv + (size_t)row * 512 + k0 + lk * 8);
      int col = nc + f * 16 + lr; if (col > V_ - 1) col = V_ - 1;
      bfm[f] = *(const s16x8*)(P.W2b + (size_t)col * 512 + k0 + lk * 8);
    }
    #pragma unroll
    for (int fi = 0; fi < 4; ++fi)
      #pragma unroll
      for (int fj = 0; fj < 4; ++fj)
        acc[fi][fj] = __builtin_amdgcn_mfma_f32_16x16x32_bf16(af[fi], bfm[fj], acc[fi][fj], 0, 0, 0);
  }
  #pragma unroll
  for (int fi = 0; fi < 4; ++fi){
    #pragma unroll
    for (int jj = 0; jj < 4; ++jj){
      const int m = mr + fi * 16 + lk * 4 + jj;
      float s = 0.f;
      #pragma unroll
      for (int fj = 0; fj < 4; ++fj){
        int n = nc + fj * 16 + lr;
        if (n < V_) s += expf(acc[fi][fj][jj] + P.b2[n]);
      }
      s += __shfl_xor(s, 1); s += __shfl_xor(s, 2);
      s += __shfl_xor(s, 4); s += __shfl_xor(s, 8);
      if (lr == 0 && m < NROW_) unsafeAtomicAdd(P.rowsum + m, s);
    }
  }
}

// label logit per row (one wave per row)
__global__ __launch_bounds__(256) void kL1(Ptrs P){
  const int wid = blockIdx.x * 4 + (threadIdx.x >> 6);
  if (wid >= NROW_) return;
  const int l = threadIdx.x & 63;
  const int t = wid >> 5, b = wid & 31;
  const int lab = (t < TO_) ? P.padded[b * TO_ + t] : 2;   // EOS=2
  float s = 0.f;
  s16x8 av = *(const s16x8*)(P.tanhv + (size_t)wid * 512 + l * 8);
  s16x8 wv = *(const s16x8*)(P.W2b + (size_t)lab * 512 + l * 8);
  #pragma unroll
  for (int e = 0; e < 8; ++e) s += b2f((unsigned short)av[e]) * b2f((unsigned short)wv[e]);
  #pragma unroll
  for (int off = 1; off < 64; off <<= 1) s += __shfl_xor(s, off);
  if (l == 0) P.lablog[wid] = s + P.b2[lab];
}

// final masked-NLL reduction
__global__ __launch_bounds__(512) void kL2(Ptrs P){
  __shared__ float ssum[8], scnt[8];
  const int tid = threadIdx.x;
  float sum = 0.f, cnt = 0.f;
  for (int rr = tid; rr < NROW_; rr += 512){
    int t = rr >> 5, b = rr & 31;
    int lab = (t < TO_) ? P.padded[b * TO_ + t] : 2;
    if (lab != 0){ sum += logf(P.rowsum[rr]) - P.lablog[rr]; cnt += 1.f; }
  }
  #pragma unroll
  for (int off = 1; off < 64; off <<= 1){ sum += __shfl_xor(sum, off); cnt += __shfl_xor(cnt, off); }
  if ((tid & 63) == 0){ ssum[tid >> 6] = sum; scnt[tid >> 6] = cnt; }
  __syncthreads();
  if (tid == 0){
    float S = 0.f, C = 0.f;
    for (int i = 0; i < 8; ++i){ S += ssum[i]; C += scnt[i]; }
    P.out[0] = S / fmaxf(C, 1.f);
  }
}

// ------------------------------------------------------------------
extern "C" void kernel_launch(void* const* d_in, const int* in_sizes, int n_in,
                              void* d_out, int out_size, void* d_ws, size_t ws_size,
                              hipStream_t stream){
  (void)in_sizes; (void)n_in; (void)out_size; (void)ws_size;
  Ptrs P;
  P.padded = (const int*)d_in[0];
  P.enc    = (const float*)d_in[1];
  P.emb    = (const float*)d_in[2];
  P.Wih0 = (const float*)d_in[3];  P.Whh0 = (const float*)d_in[4];
  P.bih0 = (const float*)d_in[5];  P.bhh0 = (const float*)d_in[6];
  P.Wih1 = (const float*)d_in[7];  P.Whh1 = (const float*)d_in[8];
  P.bih1 = (const float*)d_in[9];  P.bhh1 = (const float*)d_in[10];
  P.W1 = (const float*)d_in[11];   P.b1 = (const float*)d_in[12];
  P.W2 = (const float*)d_in[13];   P.b2 = (const float*)d_in[14];
  P.out = (float*)d_out;

  char* w = (char*)d_ws;
  size_t off = 0;
  auto take = [&](size_t bytes) -> void* {
    void* ptr = (void*)(w + off);
    off += (bytes + 255) & ~(size_t)255;
    return ptr;
  };
  P.mlpin  = (unsigned short*)take((size_t)T_ * B_ * 1024 * 2);   // 16.84 MB
  P.embt   = (unsigned short*)take((size_t)T_ * B_ * 512 * 2);    // 8.42 MB
  P.tanhv  = P.embt;                                              // overlay (post-kA)
  P.W0c    = (unsigned short*)take((size_t)2048 * 1536 * 2);      // 6.29 MB
  P.W1c    = (unsigned short*)take((size_t)2048 * 1024 * 2);      // 4.19 MB
  P.W2b    = P.W0c;                                               // overlay (post-kA)
  P.W1b    = (unsigned short*)take((size_t)512 * 1024 * 2);       // 1.05 MB
  P.bias0c = (float*)take(2048 * 4);
  P.bias1c = (float*)take(2048 * 4);
  P.h0T    = (ull*)take((size_t)2 * 32 * 256 * 8);
  P.h1T    = (ull*)take((size_t)2 * 32 * 256 * 8);
  P.h1fT   = (ull*)take((size_t)2 * 32 * 512 * 8);
  P.upT    = (ull*)take((size_t)2 * 32 * 8 * 512 * 8);            // 2 MB
  P.zpT    = (ull*)take((size_t)2 * 32 * 8 * 8);
  P.atT    = (ull*)take((size_t)2 * 32 * 256 * 8);
  P.rowsum = (float*)take(NROW_ * 4);
  P.lablog = (float*)take(NROW_ * 4);

  kprep<<<dim3(2048), dim3(256), 0, stream>>>(P);
  void* args[] = { (void*)&P };
  hipLaunchCooperativeKernel(kA, dim3(NB_), dim3(256), args, 0, stream);
  kprep2<<<dim3(1024), dim3(256), 0, stream>>>(P);
  kB1<<<dim3(258),  dim3(256), 0, stream>>>(P);
  kB2<<<dim3(5064), dim3(256), 0, stream>>>(P);
  kL1<<<dim3(2056), dim3(256), 0, stream>>>(P);
  kL2<<<dim3(1),    dim3(512), 0, stream>>>(P);
}

// Round 11
// 7633.628 us; speedup vs baseline: 1.1804x; 1.1431x over previous
//
#include <hip/hip_runtime.h>
#include <hip/hip_bf16.h>

// Problem constants
#define B_    32
#define TO_   256
#define T_    257        // To+1 decode steps
#define H_    512
#define V_    10000
#define TI_   1024
#define NROW_ 8224       // T_*B_
#define NB_   256        // blocks in cooperative kernel

using f32x4 = __attribute__((ext_vector_type(4))) float;
using s16x8 = __attribute__((ext_vector_type(8))) short;
typedef unsigned long long ull;

struct Ptrs {
  const int* padded;
  const float* enc;
  const float* emb;
  const float *Wih0, *Whh0, *bih0, *bhh0;
  const float *Wih1, *Whh1, *bih1, *bhh1;
  const float *W1, *b1, *W2, *b2;
  float* out;
  // workspace
  unsigned short *mlpin;   // [257][32][1024] bf16  (=[h1 | att_c])
  unsigned short *embt;    // [257][32][512] bf16; tanhv overlays after kA
  unsigned short *tanhv;   // [8224][512] bf16 (== embt region)
  unsigned short *W0c;     // [2048][1536] bf16 rows g'=j*4+q = [Wih0 | Whh0]; W2b overlays
  unsigned short *W1c;     // [2048][1024] bf16 rows g'=j*4+q = [Wih1 | Whh1]
  unsigned short *W1b;     // [512][1024] bf16
  unsigned short *W2b;     // [10000][512] bf16 (== W0c region, kprep2)
  float *bias0c, *bias1c;  // [2048] combined biases, gate-interleaved
  unsigned short *attc;    // [32][512] bf16 pre-normalized attention context
  float *upart;            // [32][8][512] f32 context partials (plain agent stores)
  float *zp;               // [32][8] softmax-denominator partials
  unsigned short *Xh0;     // [2][32][512] bf16 h0 state
  unsigned short *Xh1;     // [2][32][512] bf16 h1 state
  float *Xh1f;             // [2][32][512] f32 h1 state (attention)
  unsigned *arrX;          // [128*4] GEMM-only barrier flags
  unsigned *arrY;          // [128*4] h1-ready flags (GEMM arrive, all wait)
  unsigned *marr;          // [256*4] per-block partial-done flags
  unsigned *larr;          // [32*4]  per-batch context-ready flags
  unsigned *ibar;          // [256*4] init barrier flags
  float *rowsum;           // [8224]
  float *lablog;           // [8224]
};

__device__ __forceinline__ unsigned short f2b(float f){
  __hip_bfloat16 h = __float2bfloat16(f);
  unsigned short r; __builtin_memcpy(&r, &h, 2); return r;
}
__device__ __forceinline__ float b2f(unsigned short u){
  unsigned v = ((unsigned)u) << 16; float f; __builtin_memcpy(&f, &v, 4); return f;
}
__device__ __forceinline__ float sigf(float x){ return 1.f / (1.f + expf(-x)); }

// ---- agent-scope (device) relaxed atomics: bypass non-coherent L1/L2 ----
__device__ __forceinline__ float aldf(const float* p){
  return __hip_atomic_load(p, __ATOMIC_RELAXED, __HIP_MEMORY_SCOPE_AGENT);
}
__device__ __forceinline__ unsigned aldw(const unsigned* p){
  return __hip_atomic_load(p, __ATOMIC_RELAXED, __HIP_MEMORY_SCOPE_AGENT);
}
__device__ __forceinline__ ull aldu(const ull* p){
  return __hip_atomic_load(p, __ATOMIC_RELAXED, __HIP_MEMORY_SCOPE_AGENT);
}
__device__ __forceinline__ void astf(float* p, float v){
  __hip_atomic_store(p, v, __ATOMIC_RELAXED, __HIP_MEMORY_SCOPE_AGENT);
}
__device__ __forceinline__ void astu(ull* p, ull v){
  __hip_atomic_store(p, v, __ATOMIC_RELAXED, __HIP_MEMORY_SCOPE_AGENT);
}
__device__ __forceinline__ void astw(unsigned* p, unsigned v){
  __hip_atomic_store(p, v, __ATOMIC_RELAXED, __HIP_MEMORY_SCOPE_AGENT);
}
#define DRAIN asm volatile("s_waitcnt vmcnt(0)" ::: "memory")

// full-grid init barrier (flag array, ph=1)
__device__ __forceinline__ void gbarInit(unsigned* bar){
  DRAIN; __syncthreads();
  if (threadIdx.x < 64){
    const int l = threadIdx.x;
    if (l == 0) astw(bar + blockIdx.x * 4, 1u);
    for (;;){
      unsigned f0 = aldw(bar + (l      ) * 4);
      unsigned f1 = aldw(bar + (l +  64) * 4);
      unsigned f2 = aldw(bar + (l + 128) * 4);
      unsigned f3 = aldw(bar + (l + 192) * 4);
      if (__all((f0 >= 1u) & (f1 >= 1u) & (f2 >= 1u) & (f3 >= 1u))) break;
      __builtin_amdgcn_s_sleep(1);
    }
  }
  __syncthreads();
}

// ------------------------------------------------------------------
__global__ __launch_bounds__(256) void kprep(Ptrs P){
  const int stride = gridDim.x * blockDim.x;
  const int i0 = blockIdx.x * blockDim.x + threadIdx.x;
  for (int i = i0; i < 128 * 4; i += stride){ P.arrX[i] = 0u; P.arrY[i] = 0u; }
  for (int i = i0; i < 256 * 4; i += stride){ P.marr[i] = 0u; P.ibar[i] = 0u; }
  for (int i = i0; i < 32 * 4; i += stride) P.larr[i] = 0u;
  for (int i = i0; i < T_ * B_ * 512; i += stride){
    int k = i & 511, tb = i >> 9, b = tb & 31, t = tb >> 5;
    int tok = (t == 0) ? 1 : P.padded[b * TO_ + (t - 1)];
    P.embt[i] = f2b(P.emb[(size_t)tok * 512 + k]);
  }
  for (int i = i0; i < 2048 * 1536; i += stride){
    int k = i % 1536, gp = i / 1536;
    int j = gp >> 2, q = gp & 3, g = q * 512 + j;
    float v = (k < 1024) ? P.Wih0[(size_t)g * 1024 + k] : P.Whh0[(size_t)g * 512 + (k - 1024)];
    P.W0c[i] = f2b(v);
  }
  for (int i = i0; i < 2048 * 1024; i += stride){
    int k = i & 1023, gp = i >> 10;
    int j = gp >> 2, q = gp & 3, g = q * 512 + j;
    float v = (k < 512) ? P.Wih1[(size_t)g * 512 + k] : P.Whh1[(size_t)g * 512 + (k - 512)];
    P.W1c[i] = f2b(v);
  }
  for (int i = i0; i < 2048; i += stride){
    int j = i >> 2, q = i & 3, g = q * 512 + j;
    P.bias0c[i] = P.bih0[g] + P.bhh0[g];
    P.bias1c[i] = P.bih1[g] + P.bhh1[g];
  }
  for (int i = i0; i < 512 * 1024; i += stride) P.W1b[i] = f2b(P.W1[i]);
  for (int i = i0; i < NROW_; i += stride) P.rowsum[i] = 0.f;
}

__global__ __launch_bounds__(256) void kprep2(Ptrs P){
  const int stride = gridDim.x * blockDim.x;
  const int i0 = blockIdx.x * blockDim.x + threadIdx.x;
  for (int i = i0; i < V_ * 512; i += stride) P.W2b[i] = f2b(P.W2[i]);
}

// ------------------------------------------------------------------
// Phase A. Per step t:
//  GEMM blocks (0-127): poll larr>=t ; S1 GEMM -> Xh0 ; arrX ; S2 GEMM -> h1 ;
//                       arrive arrY ; [join S34]
//  All blocks: wait arrY>=t+1 ; S34 scores+partials ; marr flag.
//  Reducers (128-159, rb=bb-128): poll marr[rb][0..7] ; reduce 8 partials+Z ;
//                       publish attc bf16 + mlpin att_c ; larr flag.
__global__ __launch_bounds__(256, 1) void kA(Ptrs P){
  __shared__ __align__(16) unsigned short enc_s[128 * 512]; // 128 KB, XOR-swizzled
  __shared__ float h1_s[512];
  __shared__ float w_s[128];
  __shared__ float gate_s[2][32][17];
  __shared__ float h_s[32][4];
  __shared__ float zred[2];
  const int bb = blockIdx.x, tid = threadIdx.x;
  const int b_att = bb >> 3, tc = bb & 7;

  { // stage encoder slice -> LDS bf16 with byte^((row&7)<<4) swizzle
    const float* ep = P.enc + ((size_t)b_att * TI_ + (size_t)tc * 128) * H_;
    for (int idx = tid; idx < 128 * 512; idx += 256){
      int r = idx >> 9;
      unsigned byteoff = ((unsigned)idx * 2u) ^ ((unsigned)(r & 7) << 4);
      enc_s[byteoff >> 1] = f2b(ep[idx]);
    }
  }
  { // zero recurrent state + attc
    int g = bb * 256 + tid;
    if (g < 16384){ astw((unsigned*)P.Xh0 + g, 0u); astw((unsigned*)P.Xh1 + g, 0u); }
    if (g < 32768) astf(P.Xh1f + g, 0.f);
    if (g < 8192)  astw((unsigned*)P.attc + g, 0u);
  }
  gbarInit(P.ibar);

  const int wv = tid >> 6, l = tid & 63, lr = l & 15, lk = l >> 4;
  const int bh = wv & 1, kh = wv >> 1;          // batch-half, K-half
  const int batch = bh * 16 + lr;
  const int eidx = tid - 128, eb = eidx >> 2, ejl = eidx & 3;
  const bool isGemm = bb < 128;
  const int rb = bb - 128; const bool isRed = (rb >= 0 && rb < 32);
  float c0r = 0.f, c1r = 0.f;

  for (int t = 0; t < T_; ++t){
    const int p = t & 1, pp = p ^ 1;
    const unsigned tv = (unsigned)t + 1u;
    if (isGemm){
      // ---- wait: att context (t-1) published ----
      if (t > 0 && tid < 64){
        const unsigned want = tv - 1u;
        for (;;){
          unsigned f = (tid < 32) ? aldw(P.larr + tid * 4) : want;
          if (__all(f >= want)) break;
          __builtin_amdgcn_s_sleep(1);
        }
      }
      __syncthreads();
      // ---- S1: layer-0 GEMM (K split across wave pairs) ----
      {
        const unsigned short* Brow = P.W0c + (size_t)(bb * 16 + lr) * 1536;
        const unsigned short* Erow = P.embt + ((size_t)t * 32 + batch) * 512;
        const ull* Arow = (const ull*)(P.attc + batch * 512);
        const ull* Hrow = (const ull*)(P.Xh0 + pp * 16384 + batch * 512);
        f32x4 acc = {0.f, 0.f, 0.f, 0.f};
        #pragma unroll
        for (int ks = 0; ks < 8; ++ks){
          const int kb = (kh * 8 + ks) * 32 + lk * 8;
          s16x8 a = *(const s16x8*)(Erow + kb);
          s16x8 b = *(const s16x8*)(Brow + kb);
          acc = __builtin_amdgcn_mfma_f32_16x16x32_bf16(a, b, acc, 0, 0, 0);
        }
        #pragma unroll
        for (int ks = 0; ks < 8; ++ks){
          const int kb = (kh * 8 + ks) * 32 + lk * 8;
          ull d0 = aldu(Arow + (kb >> 2)), d1 = aldu(Arow + (kb >> 2) + 1);
          s16x8 a; __builtin_memcpy(&a, &d0, 8); __builtin_memcpy(((char*)&a) + 8, &d1, 8);
          s16x8 b = *(const s16x8*)(Brow + 512 + kb);
          acc = __builtin_amdgcn_mfma_f32_16x16x32_bf16(a, b, acc, 0, 0, 0);
        }
        #pragma unroll
        for (int ks = 0; ks < 8; ++ks){
          const int kb = (kh * 8 + ks) * 32 + lk * 8;
          ull d0 = aldu(Hrow + (kb >> 2)), d1 = aldu(Hrow + (kb >> 2) + 1);
          s16x8 a; __builtin_memcpy(&a, &d0, 8); __builtin_memcpy(((char*)&a) + 8, &d1, 8);
          s16x8 b = *(const s16x8*)(Brow + 1024 + kb);
          acc = __builtin_amdgcn_mfma_f32_16x16x32_bf16(a, b, acc, 0, 0, 0);
        }
        #pragma unroll
        for (int j = 0; j < 4; ++j) gate_s[kh][bh * 16 + lk * 4 + j][lr] = acc[j];
      }
      __syncthreads();
      if (tid >= 128){
        const float* bs = P.bias0c + bb * 16 + ejl * 4;
        float ii = sigf (gate_s[0][eb][ejl * 4 + 0] + gate_s[1][eb][ejl * 4 + 0] + bs[0]);
        float ff = sigf (gate_s[0][eb][ejl * 4 + 1] + gate_s[1][eb][ejl * 4 + 1] + bs[1]);
        float gg = tanhf(gate_s[0][eb][ejl * 4 + 2] + gate_s[1][eb][ejl * 4 + 2] + bs[2]);
        float oo = sigf (gate_s[0][eb][ejl * 4 + 3] + gate_s[1][eb][ejl * 4 + 3] + bs[3]);
        float cn = ff * c0r + ii * gg; c0r = cn;
        h_s[eb][ejl] = oo * tanhf(cn);
      }
      __syncthreads();
      if (tid < 32){
        unsigned short hb[4];
        #pragma unroll
        for (int jl = 0; jl < 4; ++jl) hb[jl] = f2b(h_s[tid][jl]);
        ull v; __builtin_memcpy(&v, hb, 8);
        astu((ull*)(P.Xh0 + p * 16384 + tid * 512 + bb * 4), v);
      }
      // ---- arrX: 128-block rendezvous ----
      DRAIN; __syncthreads();
      if (tid < 64){
        if (tid == 0) astw(P.arrX + bb * 4, tv);
        for (;;){
          unsigned f0 = aldw(P.arrX + tid * 4), f1 = aldw(P.arrX + (tid + 64) * 4);
          if (__all((f0 >= tv) & (f1 >= tv))) break;
          __builtin_amdgcn_s_sleep(1);
        }
      }
      __syncthreads();
      // ---- S2: layer-1 GEMM ----
      {
        const unsigned short* Brow = P.W1c + (size_t)(bb * 16 + lr) * 1024;
        const ull* H0r = (const ull*)(P.Xh0 + p * 16384 + batch * 512);
        const ull* H1r = (const ull*)(P.Xh1 + pp * 16384 + batch * 512);
        f32x4 acc = {0.f, 0.f, 0.f, 0.f};
        #pragma unroll
        for (int ks = 0; ks < 8; ++ks){
          const int kb = (kh * 8 + ks) * 32 + lk * 8;
          ull d0 = aldu(H0r + (kb >> 2)), d1 = aldu(H0r + (kb >> 2) + 1);
          s16x8 a; __builtin_memcpy(&a, &d0, 8); __builtin_memcpy(((char*)&a) + 8, &d1, 8);
          s16x8 b = *(const s16x8*)(Brow + kb);
          acc = __builtin_amdgcn_mfma_f32_16x16x32_bf16(a, b, acc, 0, 0, 0);
        }
        #pragma unroll
        for (int ks = 0; ks < 8; ++ks){
          const int kb = (kh * 8 + ks) * 32 + lk * 8;
          ull d0 = aldu(H1r + (kb >> 2)), d1 = aldu(H1r + (kb >> 2) + 1);
          s16x8 a; __builtin_memcpy(&a, &d0, 8); __builtin_memcpy(((char*)&a) + 8, &d1, 8);
          s16x8 b = *(const s16x8*)(Brow + 512 + kb);
          acc = __builtin_amdgcn_mfma_f32_16x16x32_bf16(a, b, acc, 0, 0, 0);
        }
        #pragma unroll
        for (int j = 0; j < 4; ++j) gate_s[kh][bh * 16 + lk * 4 + j][lr] = acc[j];
      }
      __syncthreads();
      if (tid >= 128){
        const float* bs = P.bias1c + bb * 16 + ejl * 4;
        float ii = sigf (gate_s[0][eb][ejl * 4 + 0] + gate_s[1][eb][ejl * 4 + 0] + bs[0]);
        float ff = sigf (gate_s[0][eb][ejl * 4 + 1] + gate_s[1][eb][ejl * 4 + 1] + bs[1]);
        float gg = tanhf(gate_s[0][eb][ejl * 4 + 2] + gate_s[1][eb][ejl * 4 + 2] + bs[2]);
        float oo = sigf (gate_s[0][eb][ejl * 4 + 3] + gate_s[1][eb][ejl * 4 + 3] + bs[3]);
        float cn = ff * c1r + ii * gg; c1r = cn;
        h_s[eb][ejl] = oo * tanhf(cn);
      }
      __syncthreads();
      if (tid < 32){
        unsigned short hb[4];
        #pragma unroll
        for (int jl = 0; jl < 4; ++jl) hb[jl] = f2b(h_s[tid][jl]);
        ull vb; __builtin_memcpy(&vb, hb, 8);
        astu((ull*)(P.Xh1 + p * 16384 + tid * 512 + bb * 4), vb);
        *(ull*)(P.mlpin + ((size_t)t * 32 + tid) * 1024 + bb * 4) = vb;
        ull w0, w1;
        __builtin_memcpy(&w0, &h_s[tid][0], 8);
        __builtin_memcpy(&w1, &h_s[tid][2], 8);
        ull* dst = (ull*)P.Xh1f + ((p * 16384 + tid * 512 + bb * 4) >> 1);
        astu(dst, w0); astu(dst + 1, w1);
      }
      DRAIN; __syncthreads();
      if (tid == 0) astw(P.arrY + bb * 4, tv);
    }
    // ---- arrY wait: h1(t) ready (all blocks) ----
    if (tid < 64){
      for (;;){
        unsigned f0 = aldw(P.arrY + tid * 4), f1 = aldw(P.arrY + (tid + 64) * 4);
        if (__all((f0 >= tv) & (f1 >= tv))) break;
        __builtin_amdgcn_s_sleep(1);
      }
    }
    __syncthreads();
    // ---- S34: scores + softmax partials + context partials ----
    {
      ull v = aldu((const ull*)(P.Xh1f + p * 16384 + b_att * 512) + tid);
      float f2[2]; __builtin_memcpy(f2, &v, 8);
      h1_s[tid * 2] = f2[0]; h1_s[tid * 2 + 1] = f2[1];
    }
    __syncthreads();
    {
      const int ti_l = tid >> 1, half = tid & 1;
      float s = 0.f;
      const unsigned swz = (unsigned)(ti_l & 7) << 4;
      for (int h8 = half * 256; h8 < half * 256 + 256; h8 += 8){
        unsigned byteoff = ((unsigned)(ti_l * 512 + h8) * 2u) ^ swz;
        s16x8 ev = *(const s16x8*)((const char*)enc_s + byteoff);
        #pragma unroll
        for (int e = 0; e < 8; ++e) s += b2f((unsigned short)ev[e]) * h1_s[h8 + e];
      }
      s += __shfl_xor(s, 1);
      if (half == 0) w_s[ti_l] = expf(s);       // no max-shift: |s| << 88
    }
    __syncthreads();
    {
      if (tid < 128){
        float z = w_s[tid];
        #pragma unroll
        for (int off = 1; off < 64; off <<= 1) z += __shfl_xor(z, off);
        if ((tid & 63) == 0) zred[tid >> 6] = z;
      }
      float a0 = 0.f, a1 = 0.f;
      const int hc = tid * 2;
      for (int ti = 0; ti < 128; ++ti){
        const float wvv = w_s[ti];
        unsigned byteoff = ((unsigned)(ti * 1024 + hc * 2)) ^ ((unsigned)(ti & 7) << 4);
        unsigned pk = *(const unsigned*)((const char*)enc_s + byteoff);
        a0 += wvv * b2f((unsigned short)(pk & 0xffffu));
        a1 += wvv * b2f((unsigned short)(pk >> 16));
      }
      float f2[2] = {a0, a1};
      ull pv; __builtin_memcpy(&pv, f2, 8);
      astu((ull*)(P.upart + ((size_t)b_att * 8 + tc) * 512 + hc), pv);
      __syncthreads();
      if (tid == 0) astf(P.zp + b_att * 8 + tc, zred[0] + zred[1]);
      DRAIN; __syncthreads();
      if (tid == 0) astw(P.marr + (b_att * 8 + tc) * 4, tv);
    }
    // ---- reducer tail: publish attc(t) ----
    if (isRed){
      if (tid < 64){
        for (;;){
          unsigned f = (tid < 8) ? aldw(P.marr + (rb * 8 + tid) * 4) : tv;
          if (__all(f >= tv)) break;
          __builtin_amdgcn_s_sleep(1);
        }
      }
      __syncthreads();
      const int hc = tid * 2;
      float s0 = 0.f, s1 = 0.f, zs = 0.f;
      #pragma unroll
      for (int c = 0; c < 8; ++c){
        ull v = aldu((const ull*)(P.upart + ((size_t)rb * 8 + c) * 512 + hc));
        float f2[2]; __builtin_memcpy(f2, &v, 8);
        s0 += f2[0]; s1 += f2[1];
        zs += aldf(P.zp + rb * 8 + c);
      }
      const float rZ = 1.f / zs;
      unsigned pk = (unsigned)f2b(s0 * rZ) | ((unsigned)f2b(s1 * rZ) << 16);
      astw(((unsigned*)P.attc) + rb * 256 + tid, pk);
      *(unsigned*)(P.mlpin + ((size_t)t * 32 + rb) * 1024 + 512 + hc) = pk;
      DRAIN; __syncthreads();
      if (tid == 0) astw(P.larr + rb * 4, tv);
    }
  }
}

// ------------------------------------------------------------------
// B1: tanhv = tanh(mlpin @ W1^T + b1)   M=8224 N=512 K=1024, bf16 MFMA
__global__ __launch_bounds__(256) void kB1(Ptrs P){
  const int wid = blockIdx.x * 4 + (threadIdx.x >> 6);
  if (wid >= 129 * 8) return;
  const int mt = wid >> 3, nt = wid & 7;
  const int l = threadIdx.x & 63, lr = l & 15, lk = l >> 4;
  const int mr = mt * 64, nc = nt * 64;
  f32x4 acc[4][4] = {};
  for (int k0 = 0; k0 < 1024; k0 += 32){
    s16x8 af[4], bfm[4];
    #pragma unroll
    for (int f = 0; f < 4; ++f){
      int row = mr + f * 16 + lr; if (row > NROW_ - 1) row = NROW_ - 1;
      af[f] = *(const s16x8*)(P.mlpin + (size_t)row * 1024 + k0 + lk * 8);
      int col = nc + f * 16 + lr;
      bfm[f] = *(const s16x8*)(P.W1b + (size_t)col * 1024 + k0 + lk * 8);
    }
    #pragma unroll
    for (int fi = 0; fi < 4; ++fi)
      #pragma unroll
      for (int fj = 0; fj < 4; ++fj)
        acc[fi][fj] = __builtin_amdgcn_mfma_f32_16x16x32_bf16(af[fi], bfm[fj], acc[fi][fj], 0, 0, 0);
  }
  #pragma unroll
  for (int fi = 0; fi < 4; ++fi){
    #pragma unroll
    for (int jj = 0; jj < 4; ++jj){
      int m = mr + fi * 16 + lk * 4 + jj;
      if (m >= NROW_) continue;
      #pragma unroll
      for (int fj = 0; fj < 4; ++fj){
        int n = nc + fj * 16 + lr;
        P.tanhv[(size_t)m * 512 + n] = f2b(tanhf(acc[fi][fj][jj] + P.b1[n]));
      }
    }
  }
}

// B2: logits = tanhv @ W2^T + b2, fused exp-rowsum.  M=8224 N=10000 K=512
__global__ __launch_bounds__(256) void kB2(Ptrs P){
  const int wid = blockIdx.x * 4 + (threadIdx.x >> 6);
  if (wid >= 129 * 157) return;
  const int mt = wid / 157, nt = wid % 157;
  const int l = threadIdx.x & 63, lr = l & 15, lk = l >> 4;
  const int mr = mt * 64, nc = nt * 64;
  f32x4 acc[4][4] = {};
  for (int k0 = 0; k0 < 512; k0 += 32){
    s16x8 af[4], bfm[4];
    #pragma unroll
    for (int f = 0; f < 4; ++f){
      int row = mr + f * 16 + lr; if (row > NROW_ - 1) row = NROW_ - 1;
      af[f] = *(const s16x8*)(P.tanhv + (size_t)row * 512 + k0 + lk * 8);
      int col = nc + f * 16 + lr; if (col > V_ - 1) col = V_ - 1;
      bfm[f] = *(const s16x8*)(P.W2b + (size_t)col * 512 + k0 + lk * 8);
    }
    #pragma unroll
    for (int fi = 0; fi < 4; ++fi)
      #pragma unroll
      for (int fj = 0; fj < 4; ++fj)
        acc[fi][fj] = __builtin_amdgcn_mfma_f32_16x16x32_bf16(af[fi], bfm[fj], acc[fi][fj], 0, 0, 0);
  }
  #pragma unroll
  for (int fi = 0; fi < 4; ++fi){
    #pragma unroll
    for (int jj = 0; jj < 4; ++jj){
      const int m = mr + fi * 16 + lk * 4 + jj;
      float s = 0.f;
      #pragma unroll
      for (int fj = 0; fj < 4; ++fj){
        int n = nc + fj * 16 + lr;
        if (n < V_) s += expf(acc[fi][fj][jj] + P.b2[n]);
      }
      s += __shfl_xor(s, 1); s += __shfl_xor(s, 2);
      s += __shfl_xor(s, 4); s += __shfl_xor(s, 8);
      if (lr == 0 && m < NROW_) unsafeAtomicAdd(P.rowsum + m, s);
    }
  }
}

// label logit per row (one wave per row)
__global__ __launch_bounds__(256) void kL1(Ptrs P){
  const int wid = blockIdx.x * 4 + (threadIdx.x >> 6);
  if (wid >= NROW_) return;
  const int l = threadIdx.x & 63;
  const int t = wid >> 5, b = wid & 31;
  const int lab = (t < TO_) ? P.padded[b * TO_ + t] : 2;   // EOS=2
  float s = 0.f;
  s16x8 av = *(const s16x8*)(P.tanhv + (size_t)wid * 512 + l * 8);
  s16x8 wv = *(const s16x8*)(P.W2b + (size_t)lab * 512 + l * 8);
  #pragma unroll
  for (int e = 0; e < 8; ++e) s += b2f((unsigned short)av[e]) * b2f((unsigned short)wv[e]);
  #pragma unroll
  for (int off = 1; off < 64; off <<= 1) s += __shfl_xor(s, off);
  if (l == 0) P.lablog[wid] = s + P.b2[lab];
}

// final masked-NLL reduction
__global__ __launch_bounds__(512) void kL2(Ptrs P){
  __shared__ float ssum[8], scnt[8];
  const int tid = threadIdx.x;
  float sum = 0.f, cnt = 0.f;
  for (int rr = tid; rr < NROW_; rr += 512){
    int t = rr >> 5, b = rr & 31;
    int lab = (t < TO_) ? P.padded[b * TO_ + t] : 2;
    if (lab != 0){ sum += logf(P.rowsum[rr]) - P.lablog[rr]; cnt += 1.f; }
  }
  #pragma unroll
  for (int off = 1; off < 64; off <<= 1){ sum += __shfl_xor(sum, off); cnt += __shfl_xor(cnt, off); }
  if ((tid & 63) == 0){ ssum[tid >> 6] = sum; scnt[tid >> 6] = cnt; }
  __syncthreads();
  if (tid == 0){
    float S = 0.f, C = 0.f;
    for (int i = 0; i < 8; ++i){ S += ssum[i]; C += scnt[i]; }
    P.out[0] = S / fmaxf(C, 1.f);
  }
}

// ------------------------------------------------------------------
extern "C" void kernel_launch(void* const* d_in, const int* in_sizes, int n_in,
                              void* d_out, int out_size, void* d_ws, size_t ws_size,
                              hipStream_t stream){
  (void)in_sizes; (void)n_in; (void)out_size; (void)ws_size;
  Ptrs P;
  P.padded = (const int*)d_in[0];
  P.enc    = (const float*)d_in[1];
  P.emb    = (const float*)d_in[2];
  P.Wih0 = (const float*)d_in[3];  P.Whh0 = (const float*)d_in[4];
  P.bih0 = (const float*)d_in[5];  P.bhh0 = (const float*)d_in[6];
  P.Wih1 = (const float*)d_in[7];  P.Whh1 = (const float*)d_in[8];
  P.bih1 = (const float*)d_in[9];  P.bhh1 = (const float*)d_in[10];
  P.W1 = (const float*)d_in[11];   P.b1 = (const float*)d_in[12];
  P.W2 = (const float*)d_in[13];   P.b2 = (const float*)d_in[14];
  P.out = (float*)d_out;

  char* w = (char*)d_ws;
  size_t off = 0;
  auto take = [&](size_t bytes) -> void* {
    void* ptr = (void*)(w + off);
    off += (bytes + 255) & ~(size_t)255;
    return ptr;
  };
  P.mlpin  = (unsigned short*)take((size_t)T_ * B_ * 1024 * 2);   // 16.84 MB
  P.embt   = (unsigned short*)take((size_t)T_ * B_ * 512 * 2);    // 8.42 MB
  P.tanhv  = P.embt;                                              // overlay (post-kA)
  P.W0c    = (unsigned short*)take((size_t)2048 * 1536 * 2);      // 6.29 MB
  P.W1c    = (unsigned short*)take((size_t)2048 * 1024 * 2);      // 4.19 MB
  P.W2b    = P.W0c;                                               // overlay (post-kA)
  P.W1b    = (unsigned short*)take((size_t)512 * 1024 * 2);       // 1.05 MB
  P.bias0c = (float*)take(2048 * 4);
  P.bias1c = (float*)take(2048 * 4);
  P.attc   = (unsigned short*)take(32 * 512 * 2);
  P.upart  = (float*)take((size_t)32 * 8 * 512 * 4);              // 512 KB
  P.zp     = (float*)take(32 * 8 * 4);
  P.Xh0    = (unsigned short*)take(2 * 32 * 512 * 2);
  P.Xh1    = (unsigned short*)take(2 * 32 * 512 * 2);
  P.Xh1f   = (float*)take(2 * 32 * 512 * 4);
  P.arrX   = (unsigned*)take(128 * 4 * 4);
  P.arrY   = (unsigned*)take(128 * 4 * 4);
  P.marr   = (unsigned*)take(256 * 4 * 4);
  P.larr   = (unsigned*)take(32 * 4 * 4);
  P.ibar   = (unsigned*)take(256 * 4 * 4);
  P.rowsum = (float*)take(NROW_ * 4);
  P.lablog = (float*)take(NROW_ * 4);

  kprep<<<dim3(2048), dim3(256), 0, stream>>>(P);
  void* args[] = { (void*)&P };
  hipLaunchCooperativeKernel(kA, dim3(NB_), dim3(256), args, 0, stream);
  kprep2<<<dim3(1024), dim3(256), 0, stream>>>(P);
  kB1<<<dim3(258),  dim3(256), 0, stream>>>(P);
  kB2<<<dim3(5064), dim3(256), 0, stream>>>(P);
  kL1<<<dim3(2056), dim3(256), 0, stream>>>(P);
  kL2<<<dim3(1),    dim3(512), 0, stream>>>(P);
}